// Round 9
// baseline (151.067 us; speedup 1.0000x reference)
//
#include <hip/hip_runtime.h>
#include <math.h>

#define B_  32
#define C_  256
#define HW_ 4096
#define LN_EPS 1e-5f

typedef __attribute__((ext_vector_type(4))) float f32x4;
typedef __attribute__((ext_vector_type(8))) short bf16x8;
typedef __attribute__((ext_vector_type(4))) unsigned u32x4;
typedef __attribute__((ext_vector_type(2))) unsigned u32x2;

__device__ __forceinline__ float hsig(float v) {
    return fminf(fmaxf((v + 3.0f) * (1.0f / 6.0f), 0.0f), 1.0f);
}
// softmax logit: a*hsig(ca*sa) + (1-a)*hsig(ca+sa); always in [0,1]
__device__ __forceinline__ float tval(float ca, float a, float sav) {
    return a * hsig(ca * sav) + (1.0f - a) * hsig(ca + sav);
}
__device__ __forceinline__ unsigned short f2bf(float f) {
    unsigned u = __float_as_uint(f);
    unsigned r = (u + 0x7fffu + ((u >> 16) & 1u)) >> 16;   // RNE
    return (unsigned short)r;
}
__device__ __forceinline__ float bf2f(unsigned short h) {
    return __uint_as_float(((unsigned)h) << 16);
}
// Bs swizzle: conflict-free for b64 staging writes, b128 B-frag reads, 8B epilogue reads
__device__ __forceinline__ int bswz(int n) {
    return ((n & 7) ^ ((n >> 3) & 7)) << 4;
}

// =====================================================================
// NEW PATH: xbf in natural [b][c][hw] bf16 layout.
// =====================================================================

// ---- K1: one x pass -> sa + xs partials + xbf ----
// Round 9: (a) unroll 4->8 (more loads in flight per wave; VGPR was 24, room to 64);
// (b) __launch_bounds__(1024, 8) pins the 64-VGPR budget for 8 waves/SIMD;
// (c) nontemporal x loads — x is read ONCE in the whole pipeline; keep its 134MB
// out of L2/L3 so the xbf being written stays resident for stats4/out3.
__global__ __launch_bounds__(1024, 8) void k_pass1c(
    const float* __restrict__ x, const float* __restrict__ w1,
    float* __restrict__ sa, float* __restrict__ xs_part,
    unsigned short* __restrict__ xbf)
{
    __shared__ float sw1[C_];
    __shared__ float sred[16][256];
    __shared__ float xsl[C_];
    int hwq = blockIdx.x, b = blockIdx.y;
    int tid = threadIdx.x, w = tid >> 6, l = tid & 63;
    int hw0 = hwq * 256;
    if (tid < 256) sw1[tid] = w1[tid];
    __syncthreads();
    const float* xb = x + (size_t)b * (C_ * HW_) + hw0 + l * 4;
    unsigned short* xo = xbf + (size_t)b * (C_ * HW_) + hw0 + l * 4;
    f32x4 sacc = {0.f, 0.f, 0.f, 0.f};
    #pragma unroll 8
    for (int i = 0; i < 16; ++i) {
        int c = i * 16 + w;
        f32x4 v = __builtin_nontemporal_load((const f32x4*)(xb + (size_t)c * HW_));
        sacc += sw1[c] * v;
        ushort4 o = { f2bf(v.x), f2bf(v.y), f2bf(v.z), f2bf(v.w) };
        *(ushort4*)(xo + (size_t)c * HW_) = o;
        float h = (v.x + v.y) + (v.z + v.w);
        h += __shfl_xor(h, 32); h += __shfl_xor(h, 16); h += __shfl_xor(h, 8);
        h += __shfl_xor(h, 4);  h += __shfl_xor(h, 2);  h += __shfl_xor(h, 1);
        if (l == 0) xsl[c] = h;
    }
    *(f32x4*)&sred[w][l * 4] = sacc;
    __syncthreads();
    if (tid < 256) {
        float s = 0.f;
        #pragma unroll
        for (int g = 0; g < 16; ++g) s += sred[g][tid];
        sa[(size_t)b * HW_ + hw0 + tid] = s;
        xs_part[((size_t)hwq * B_ + b) * C_ + tid] = xsl[tid];
    }
}

// ---- K2: ca = LN(hsig(bn1(conv0(mean))))  [+ fused res_w->bf16 cvt] (both paths)
__global__ void k_ca(const float* __restrict__ xs_part, const float* __restrict__ w0,
                     const float* __restrict__ b0, const float* __restrict__ w1,
                     const float* __restrict__ b1, const float* __restrict__ g,
                     const float* __restrict__ be, float* __restrict__ ca,
                     const float* __restrict__ rw, unsigned short* __restrict__ wbs,
                     int nparts) {
    int b = blockIdx.x, tid = threadIdx.x;  // 256
    __shared__ float xm[C_], t0[128], red[4];
    float xs = 0.f;
    for (int i = 0; i < nparts; ++i)
        xs += xs_part[((size_t)i * B_ + b) * C_ + tid];
    xm[tid] = xs * (1.0f / HW_);
    __syncthreads();
    if (tid < 128) {
        float s = b0[tid];
        const float* wr = w0 + tid * C_;
        for (int c = 0; c < C_; ++c) s += wr[c] * xm[c];
        t0[tid] = s;
    }
    __syncthreads();
    float s = b1[tid];
    const float* wr = w1 + tid * 128;
    for (int o = 0; o < 128; ++o) s += wr[o] * t0[o];
    float v = hsig(s);
    float sum = v;
    #pragma unroll
    for (int o = 32; o; o >>= 1) sum += __shfl_xor(sum, o);
    if ((tid & 63) == 0) red[tid >> 6] = sum;
    __syncthreads();
    float mu = (red[0] + red[1] + red[2] + red[3]) * (1.0f / C_);
    __syncthreads();
    float d = v - mu;
    float sq = d * d;
    #pragma unroll
    for (int o = 32; o; o >>= 1) sq += __shfl_xor(sq, o);
    if ((tid & 63) == 0) red[tid >> 6] = sq;
    __syncthreads();
    float var = (red[0] + red[1] + red[2] + red[3]) * (1.0f / C_);
    ca[b * C_ + tid] = d * (1.0f / sqrtf(var + LN_EPS)) * g[tid] + be[tid];

    // ---- fused: res_w fp32 -> bf16 in MFMA A-fragment order ----
    int gid = b * 256 + tid;
    int lane = gid & 63;
    int mi = (gid >> 6) & 3;
    int ks = (gid >> 8) & 7;
    int wv2 = gid >> 11;
    int m = wv2 * 64 + mi * 16 + (lane & 15);
    int kb = ks * 32 + (lane >> 4) * 8;
    const float* src = rw + m * C_ + kb;
    f32x4 a4 = *(const f32x4*)src;
    f32x4 b4 = *(const f32x4*)(src + 4);
    ushort4 o0 = { f2bf(a4.x), f2bf(a4.y), f2bf(a4.z), f2bf(a4.w) };
    ushort4 o1 = { f2bf(b4.x), f2bf(b4.y), f2bf(b4.z), f2bf(b4.w) };
    unsigned short* dst = wbs + (size_t)gid * 8;
    *(ushort4*)dst = o0;
    *(ushort4*)(dst + 4) = o1;
}

// ---- K3n: u for 2 channels per block (sa loads shared) ----
__global__ void k_u2(const float* __restrict__ sa, const float* __restrict__ ca,
                     const float* __restrict__ b1, float* __restrict__ u) {
    int bc = blockIdx.x;              // 4096
    int b = bc >> 7, c0 = (bc & 127) * 2;
    int tid = threadIdx.x;            // 64
    float ca0 = ca[b * C_ + c0], ca1 = ca[b * C_ + c0 + 1];
    float bias = b1[0];
    const float* sp = sa + (size_t)b * HW_;
    float s0 = 0.f, s1 = 0.f;
    for (int i = 0; i < 16; ++i) {
        f32x4 v = *(const f32x4*)(sp + i * 256 + tid * 4);
        #pragma unroll
        for (int j = 0; j < 4; ++j) {
            float sv = v[j] + bias;
            s0 += hsig(ca0 * sv) + hsig(ca0 + sv);
            s1 += hsig(ca1 * sv) + hsig(ca1 + sv);
        }
    }
    #pragma unroll
    for (int o = 32; o; o >>= 1) { s0 += __shfl_xor(s0, o); s1 += __shfl_xor(s1, o); }
    if (tid == 0) {
        u[b * C_ + c0]     = s0 * (1.0f / HW_);
        u[b * C_ + c0 + 1] = s1 * (1.0f / HW_);
    }
}

// ---- K4: a[b,c] = softmax_c(sk_w2 @ (sk_w1 @ u)) (both paths) ----
__global__ void k_a(const float* __restrict__ u, const float* __restrict__ w1,
                    const float* __restrict__ w2, float* __restrict__ aout) {
    int b = blockIdx.x, tid = threadIdx.x;  // 256
    __shared__ float uu[C_], v0[128], red[4];
    uu[tid] = u[b * C_ + tid];
    __syncthreads();
    if (tid < 128) {
        float s = 0.f;
        const float* wr = w1 + tid * C_;
        for (int c = 0; c < C_; ++c) s += wr[c] * uu[c];
        v0[tid] = s;
    }
    __syncthreads();
    float s = 0.f;
    const float* wr = w2 + tid * 128;
    for (int o = 0; o < 128; ++o) s += wr[o] * v0[o];
    float m = s;
    #pragma unroll
    for (int o = 32; o; o >>= 1) m = fmaxf(m, __shfl_xor(m, o));
    if ((tid & 63) == 0) red[tid >> 6] = m;
    __syncthreads();
    m = fmaxf(fmaxf(red[0], red[1]), fmaxf(red[2], red[3]));
    __syncthreads();
    float e = __expf(s - m);
    float se = e;
    #pragma unroll
    for (int o = 32; o; o >>= 1) se += __shfl_xor(se, o);
    if ((tid & 63) == 0) red[tid >> 6] = se;
    __syncthreads();
    float tot = red[0] + red[1] + red[2] + red[3];
    aout[b * C_ + tid] = e / tot;
}

// ---- K5n: row stats for 2 channels per block (sa loads shared, xbf bf16) ----
__global__ void k_stats4(const unsigned short* __restrict__ xbf, const float* __restrict__ sa,
                         const float* __restrict__ b1,
                         const float* __restrict__ ca, const float* __restrict__ aw,
                         const float* __restrict__ res_b, f32x4* __restrict__ st4) {
    int blk = blockIdx.x;             // 4096
    int b = blk >> 7, c0 = (blk & 127) * 2;
    int bc0 = b * C_ + c0;
    int tid = threadIdx.x;            // 256
    float ca0 = ca[bc0],     a0 = aw[bc0];
    float ca1 = ca[bc0 + 1], a1 = aw[bc0 + 1];
    float bias = b1[0];
    const float* sp = sa + (size_t)b * HW_;
    const unsigned* xp0 = (const unsigned*)(xbf + (size_t)bc0 * HW_);
    const unsigned* xp1 = (const unsigned*)(xbf + (size_t)(bc0 + 1) * HW_);
    float se0 = 0.f, xe0 = 0.f, se1 = 0.f, xe1 = 0.f;
    #pragma unroll
    for (int i = 0; i < 4; ++i) {
        f32x4 s4 = *(const f32x4*)(sp + i * 1024 + tid * 4);
        u32x2 xa = *(const u32x2*)(xp0 + i * 512 + tid * 2);
        u32x2 xc = *(const u32x2*)(xp1 + i * 512 + tid * 2);
        float va[4], vc[4];
        va[0] = bf2f((unsigned short)(xa[0] & 0xffffu));
        va[1] = bf2f((unsigned short)(xa[0] >> 16));
        va[2] = bf2f((unsigned short)(xa[1] & 0xffffu));
        va[3] = bf2f((unsigned short)(xa[1] >> 16));
        vc[0] = bf2f((unsigned short)(xc[0] & 0xffffu));
        vc[1] = bf2f((unsigned short)(xc[0] >> 16));
        vc[2] = bf2f((unsigned short)(xc[1] & 0xffffu));
        vc[3] = bf2f((unsigned short)(xc[1] >> 16));
        #pragma unroll
        for (int j = 0; j < 4; ++j) {
            float sv = s4[j] + bias;
            float e0 = __expf(tval(ca0, a0, sv));
            float e1 = __expf(tval(ca1, a1, sv));
            se0 += e0; xe0 += va[j] * e0;
            se1 += e1; xe1 += vc[j] * e1;
        }
    }
    __shared__ float red[4][4];
    #pragma unroll
    for (int o = 32; o; o >>= 1) {
        se0 += __shfl_xor(se0, o); xe0 += __shfl_xor(xe0, o);
        se1 += __shfl_xor(se1, o); xe1 += __shfl_xor(xe1, o);
    }
    if ((tid & 63) == 0) {
        int w = tid >> 6;
        red[0][w] = se0; red[1][w] = xe0; red[2][w] = se1; red[3][w] = xe1;
    }
    __syncthreads();
    if (tid == 0) {
        float S0 = red[0][0] + red[0][1] + red[0][2] + red[0][3];
        float X0 = red[1][0] + red[1][1] + red[1][2] + red[1][3];
        float S1 = red[2][0] + red[2][1] + red[2][2] + red[2][3];
        float X1 = red[3][0] + red[3][1] + red[3][2] + red[3][3];
        float r0 = 1.0f / S0, r1 = 1.0f / S1;
        f32x4 st0 = { ca0, a0, r0, X0 * r0 + res_b[c0] };
        f32x4 st1 = { ca1, a1, r1, X1 * r1 + res_b[c0 + 1] };
        st4[bc0] = st0;
        st4[bc0 + 1] = st1;
    }
}

// ---- K6b: out = res_w@x (bf16 MFMA) + x*p + addv.
// launch_bounds (256,3): VGPR 104, no spills. nontemporal out stores keep the
// 134MB write stream out of L2/L3 (FETCH 68->44MB measured in round 7).
__global__ __launch_bounds__(256, 3) void k_out3(
    const unsigned short* __restrict__ xbf, const unsigned short* __restrict__ wbs,
    const float* __restrict__ sa, const float* __restrict__ b1,
    const f32x4* __restrict__ st4, float* __restrict__ out)
{
    __shared__ __align__(16) unsigned short Bs[64 * 256];  // [n][k-pair] bf16, swizzled, 32 KB
    __shared__ f32x4 sst[C_];
    __shared__ float ssa[64];

    int b = blockIdx.x, tile = blockIdx.y;
    int n0 = tile * 64;
    int tid = threadIdx.x;       // 256
    int w = tid >> 6, lane = tid & 63;
    int hwc = tid & 7;           // 8-hw chunk within the 64-wide tile
    int cq  = tid >> 3;          // 0..31 -> 4 consecutive c rows per iteration

    // ---- issue staging loads first (overlap with af/sst/ssa loads) ----
    const unsigned short* xb = xbf + (size_t)b * (C_ * HW_) + n0 + hwc * 8;
    u32x4 ld[2][4];
    #pragma unroll
    for (int it = 0; it < 2; ++it) {
        int c0 = it * 128 + cq * 4;
        #pragma unroll
        for (int r = 0; r < 4; ++r)
            ld[it][r] = *(const u32x4*)(xb + (size_t)(c0 + r) * HW_);
    }

    bf16x8 af[2][4];
    const bf16x8* wp = (const bf16x8*)wbs;
    #pragma unroll
    for (int ks2 = 0; ks2 < 2; ++ks2)
        #pragma unroll
        for (int mi = 0; mi < 4; ++mi)
            af[ks2][mi] = wp[(size_t)(((w * 8 + ks2) * 4 + mi) * 64 + lane)];

    sst[tid] = st4[b * C_ + tid];
    if (tid < 64) ssa[tid] = sa[(size_t)b * HW_ + n0 + tid] + b1[0];

    // ---- interleave c-pairs + swizzled ds_write_b64 ----
    #pragma unroll
    for (int it = 0; it < 2; ++it) {
        int kp0 = it * 64 + cq * 2;
        #pragma unroll
        for (int e = 0; e < 8; ++e) {
            int n = hwc * 8 + e;
            unsigned a0 = ld[it][0][e >> 1], b0v = ld[it][1][e >> 1];
            unsigned a1 = ld[it][2][e >> 1], b1v = ld[it][3][e >> 1];
            unsigned d0, d1;
            if (e & 1) {
                d0 = (a0 >> 16) | (b0v & 0xffff0000u);
                d1 = (a1 >> 16) | (b1v & 0xffff0000u);
            } else {
                d0 = (a0 & 0xffffu) | (b0v << 16);
                d1 = (a1 & 0xffffu) | (b1v << 16);
            }
            int bo = (n * 512 + kp0 * 4) ^ bswz(n);
            u32x2 dd = { d0, d1 };
            *(u32x2*)((char*)Bs + bo) = dd;
        }
    }
    __syncthreads();

    f32x4 acc[4][4];
    #pragma unroll
    for (int i = 0; i < 4; ++i)
        #pragma unroll
        for (int j = 0; j < 4; ++j) acc[i][j] = (f32x4){0.f, 0.f, 0.f, 0.f};

    #pragma unroll
    for (int ksg = 0; ksg < 4; ++ksg) {
        #pragma unroll
        for (int ks2 = 0; ks2 < 2; ++ks2) {
            int ks = ksg * 2 + ks2;
            bf16x8 bfr[4];
            #pragma unroll
            for (int ni = 0; ni < 4; ++ni) {
                int n = ni * 16 + (lane & 15);
                int bo = (n * 512 + ks * 64 + (lane >> 4) * 16) ^ bswz(n);
                bfr[ni] = *(const bf16x8*)((const char*)Bs + bo);
            }
            #pragma unroll
            for (int mi = 0; mi < 4; ++mi)
                #pragma unroll
                for (int ni = 0; ni < 4; ++ni)
                    acc[mi][ni] = __builtin_amdgcn_mfma_f32_16x16x32_bf16(
                        af[ks2][mi], bfr[ni], acc[mi][ni], 0, 0, 0);
            if (ksg < 3) {   // reload this half for the next K-group (overlaps MFMAs)
                #pragma unroll
                for (int mi = 0; mi < 4; ++mi)
                    af[ks2][mi] = wp[(size_t)(((w * 8 + (ksg + 1) * 2 + ks2) * 4 + mi) * 64 + lane)];
            }
        }
    }

    // epilogue: out = acc + x*p + addv   (x re-read as bf16 from Bs; p = exp(t)/S)
    float* ob = out + (size_t)b * (C_ * HW_) + n0;
    #pragma unroll
    for (int mi = 0; mi < 4; ++mi) {
        int m0 = w * 64 + mi * 16 + (lane >> 4) * 4;
        f32x4 s0 = sst[m0 + 0];
        f32x4 s1 = sst[m0 + 1];
        f32x4 s2 = sst[m0 + 2];
        f32x4 s3 = sst[m0 + 3];
        #pragma unroll
        for (int ni = 0; ni < 4; ++ni) {
            int n = ni * 16 + (lane & 15);
            float sav = ssa[n];
            int bo = (n * 512 + m0 * 2) ^ bswz(n);
            ushort4 xv = *(const ushort4*)((const char*)Bs + bo);
            float o0 = acc[mi][ni][0] + bf2f(xv.x) * (__expf(tval(s0.x, s0.y, sav)) * s0.z) + s0.w;
            float o1 = acc[mi][ni][1] + bf2f(xv.y) * (__expf(tval(s1.x, s1.y, sav)) * s1.z) + s1.w;
            float o2 = acc[mi][ni][2] + bf2f(xv.z) * (__expf(tval(s2.x, s2.y, sav)) * s2.z) + s2.w;
            float o3 = acc[mi][ni][3] + bf2f(xv.w) * (__expf(tval(s3.x, s3.y, sav)) * s3.z) + s3.w;
            __builtin_nontemporal_store(o0, &ob[(size_t)(m0 + 0) * HW_ + n]);
            __builtin_nontemporal_store(o1, &ob[(size_t)(m0 + 1) * HW_ + n]);
            __builtin_nontemporal_store(o2, &ob[(size_t)(m0 + 2) * HW_ + n]);
            __builtin_nontemporal_store(o3, &ob[(size_t)(m0 + 3) * HW_ + n]);
        }
    }
}

// =====================================================================
// OLD PATH (fallback when workspace too small) — unchanged kernels
// =====================================================================

__global__ void k_pass1(const float* __restrict__ x, const float* __restrict__ w1,
                        float* __restrict__ sa, float* __restrict__ xs_part)
{
    int tid = threadIdx.x, wave = tid >> 6, lane = tid & 63;
    int hwq = blockIdx.x, b = blockIdx.y, ct = blockIdx.z;
    int c0 = ct * 32;
    int hw0 = hwq * 1024;
    const float* xb = x + (size_t)b * (C_ * HW_) + hw0 + tid * 4;
    __shared__ float part[32 * 4];
    f32x4 sacc = {0.f, 0.f, 0.f, 0.f};
    #pragma unroll 4
    for (int cc = 0; cc < 32; ++cc) {
        int c = c0 + cc;
        f32x4 v = *(const f32x4*)(xb + (size_t)c * HW_);
        float wv = w1[c];
        sacc += wv * v;
        float h = (v.x + v.y) + (v.z + v.w);
        h += __shfl_xor(h, 32); h += __shfl_xor(h, 16); h += __shfl_xor(h, 8);
        h += __shfl_xor(h, 4);  h += __shfl_xor(h, 2);  h += __shfl_xor(h, 1);
        if (lane == 0) part[cc * 4 + wave] = h;
    }
    float* sp = sa + (size_t)b * HW_ + hw0 + tid * 4;
    atomicAdd(sp + 0, sacc.x);
    atomicAdd(sp + 1, sacc.y);
    atomicAdd(sp + 2, sacc.z);
    atomicAdd(sp + 3, sacc.w);
    __syncthreads();
    if (tid < 32)
        xs_part[((size_t)hwq * B_ + b) * C_ + c0 + tid] =
            part[tid * 4 + 0] + part[tid * 4 + 1] + part[tid * 4 + 2] + part[tid * 4 + 3];
}

__global__ void k_u(const float* __restrict__ sa, const float* __restrict__ ca,
                    const float* __restrict__ b1, float* __restrict__ u) {
    int bc = blockIdx.x;
    int b = bc >> 8;
    int tid = threadIdx.x;  // 64
    float cav = ca[bc];
    float bias = b1[0];
    const float* sp = sa + (size_t)b * HW_;
    float s = 0.f;
    for (int i = 0; i < 16; ++i) {
        f32x4 v = *(const f32x4*)(sp + i * 256 + tid * 4);
        #pragma unroll
        for (int j = 0; j < 4; ++j) {
            float sv = v[j] + bias;
            s += hsig(cav * sv) + hsig(cav + sv);
        }
    }
    #pragma unroll
    for (int o = 32; o; o >>= 1) s += __shfl_xor(s, o);
    if (tid == 0) u[bc] = s * (1.0f / HW_);
}

__global__ void k_stats(const float* __restrict__ x, const float* __restrict__ sa,
                        const float* __restrict__ b1,
                        const float* __restrict__ ca, const float* __restrict__ aw,
                        const float* __restrict__ res_b, f32x4* __restrict__ st4) {
    int bc = blockIdx.x;
    int b = bc >> 8, c = bc & 255;
    int tid = threadIdx.x;  // 256
    float cav = ca[bc], av = aw[bc];
    float bias = b1[0];
    const float* sp = sa + (size_t)b * HW_;
    const float* xp = x + (size_t)bc * HW_;
    float se = 0.f, xe = 0.f;
    #pragma unroll
    for (int i = 0; i < 4; ++i) {
        f32x4 s4 = *(const f32x4*)(sp + i * 1024 + tid * 4);
        f32x4 x4 = *(const f32x4*)(xp + i * 1024 + tid * 4);
        #pragma unroll
        for (int j = 0; j < 4; ++j) {
            float e = __expf(tval(cav, av, s4[j] + bias));
            se += e;
            xe += x4[j] * e;
        }
    }
    __shared__ float red[4], red2[4];
    #pragma unroll
    for (int o = 32; o; o >>= 1) { se += __shfl_xor(se, o); xe += __shfl_xor(xe, o); }
    if ((tid & 63) == 0) { red[tid >> 6] = se; red2[tid >> 6] = xe; }
    __syncthreads();
    if (tid == 0) {
        float S = red[0] + red[1] + red[2] + red[3];
        float X = red2[0] + red2[1] + red2[2] + red2[3];
        float rcp = 1.0f / S;
        f32x4 st = { cav, av, rcp, X * rcp + res_b[c] };
        st4[bc] = st;
    }
}

__global__ __launch_bounds__(256, 2) void k_out(
    const float* __restrict__ x, const unsigned short* __restrict__ wbs,
    const float* __restrict__ sa, const float* __restrict__ b1,
    const f32x4* __restrict__ st4, float* __restrict__ out)
{
    __shared__ __align__(16) unsigned short Bs[64 * 256];
    __shared__ f32x4 sst[C_];
    __shared__ float ssa[64];

    int b = blockIdx.x, tile = blockIdx.y;
    int n0 = tile * 64;
    int tid = threadIdx.x;
    int w = tid >> 6, lane = tid & 63;

    const float* xb = x + (size_t)b * (C_ * HW_);

    bf16x8 af[8][4];
    #pragma unroll
    for (int ks = 0; ks < 8; ++ks)
        #pragma unroll
        for (int mi = 0; mi < 4; ++mi)
            af[ks][mi] = *(const bf16x8*)(wbs + (size_t)(((w * 8 + ks) * 4 + mi) * 64 + lane) * 8);

    sst[tid] = st4[b * C_ + tid];
    if (tid < 64) ssa[tid] = sa[(size_t)b * HW_ + n0 + tid] + b1[0];

    #pragma unroll
    for (int p2 = 0; p2 < 8; ++p2) {
        int id = p2 * 256 + tid;
        int kp = id >> 4;
        int tcn = id & 15;
        const float* g0 = xb + (size_t)(2 * kp) * HW_ + n0 + 4 * tcn;
        f32x4 v0 = *(const f32x4*)g0;
        f32x4 v1 = *(const f32x4*)(g0 + HW_);
        #pragma unroll
        for (int i = 0; i < 4; ++i) {
            int n = 4 * tcn + i;
            unsigned val = (unsigned)f2bf(v0[i]) | ((unsigned)f2bf(v1[i]) << 16);
            int bo = (n * 512 + kp * 4) ^ ((n & 7) << 4);
            *(unsigned*)((char*)Bs + bo) = val;
        }
    }
    __syncthreads();

    f32x4 acc[4][4];
    #pragma unroll
    for (int i = 0; i < 4; ++i)
        #pragma unroll
        for (int j = 0; j < 4; ++j) acc[i][j] = (f32x4){0.f, 0.f, 0.f, 0.f};

    #pragma unroll
    for (int ks = 0; ks < 8; ++ks) {
        bf16x8 bfr[4];
        #pragma unroll
        for (int ni = 0; ni < 4; ++ni) {
            int n = ni * 16 + (lane & 15);
            int bo = (n * 512 + ks * 64 + (lane >> 4) * 16) ^ ((n & 7) << 4);
            bfr[ni] = *(const bf16x8*)((const char*)Bs + bo);
        }
        #pragma unroll
        for (int mi = 0; mi < 4; ++mi)
            #pragma unroll
            for (int ni = 0; ni < 4; ++ni)
                acc[mi][ni] = __builtin_amdgcn_mfma_f32_16x16x32_bf16(
                    af[ks][mi], bfr[ni], acc[mi][ni], 0, 0, 0);
    }

    float* ob = out + (size_t)b * (C_ * HW_) + n0;
    #pragma unroll
    for (int mi = 0; mi < 4; ++mi) {
        int m0 = w * 64 + mi * 16 + (lane >> 4) * 4;
        f32x4 s0 = sst[m0 + 0];
        f32x4 s1 = sst[m0 + 1];
        f32x4 s2 = sst[m0 + 2];
        f32x4 s3 = sst[m0 + 3];
        #pragma unroll
        for (int ni = 0; ni < 4; ++ni) {
            int n = ni * 16 + (lane & 15);
            float sav = ssa[n];
            int bo = (n * 512 + m0 * 2) ^ ((n & 7) << 4);
            ushort4 xv = *(const ushort4*)((const char*)Bs + bo);
            float o0 = acc[mi][ni][0] + bf2f(xv.x) * (__expf(tval(s0.x, s0.y, sav)) * s0.z) + s0.w;
            float o1 = acc[mi][ni][1] + bf2f(xv.y) * (__expf(tval(s1.x, s1.y, sav)) * s1.z) + s1.w;
            float o2 = acc[mi][ni][2] + bf2f(xv.z) * (__expf(tval(s2.x, s2.y, sav)) * s2.z) + s2.w;
            float o3 = acc[mi][ni][3] + bf2f(xv.w) * (__expf(tval(s3.x, s3.y, sav)) * s3.z) + s3.w;
            ob[(size_t)(m0 + 0) * HW_ + n] = o0;
            ob[(size_t)(m0 + 1) * HW_ + n] = o1;
            ob[(size_t)(m0 + 2) * HW_ + n] = o2;
            ob[(size_t)(m0 + 3) * HW_ + n] = o3;
        }
    }
}

extern "C" void kernel_launch(void* const* d_in, const int* in_sizes, int n_in,
                              void* d_out, int out_size, void* d_ws, size_t ws_size,
                              hipStream_t stream) {
    (void)in_sizes; (void)n_in; (void)out_size;
    const float* x   = (const float*)d_in[0];
    const float* c0w = (const float*)d_in[1];
    const float* c0b = (const float*)d_in[2];
    const float* b1w = (const float*)d_in[3];
    const float* b1b = (const float*)d_in[4];
    const float* c1w = (const float*)d_in[5];
    const float* c1b = (const float*)d_in[6];
    const float* lng = (const float*)d_in[7];
    const float* lnb = (const float*)d_in[8];
    const float* sw1 = (const float*)d_in[9];
    const float* sw2 = (const float*)d_in[10];
    const float* rw  = (const float*)d_in[11];
    const float* rb  = (const float*)d_in[12];
    float* out = (float*)d_out;
    float* ws = (float*)d_ws;

    const size_t NEW_WS_FLOATS = (size_t)352256 + 16777216;   // ~68.5 MB
    if (ws_size >= NEW_WS_FLOATS * sizeof(float)) {
        float* sa      = ws;                         // 131072
        float* xs_part = ws + 131072;                // 16*32*256 = 131072
        float* ca      = ws + 262144;                // 8192
        float* u       = ws + 270336;                // 8192
        float* aw      = ws + 278528;                // 8192
        f32x4* st4     = (f32x4*)(ws + 286720);      // 32768 floats
        unsigned short* wbs = (unsigned short*)(ws + 319488);   // 65536 bf16
        unsigned short* xbf = (unsigned short*)(ws + 352256);   // 67.1 MB bf16 [b][c][hw]

        hipLaunchKernelGGL(k_pass1c, dim3(16, 32), dim3(1024), 0, stream, x, c1w, sa, xs_part, xbf);
        hipLaunchKernelGGL(k_ca,     dim3(32),     dim3(256),  0, stream, xs_part, c0w, c0b, b1w, b1b, lng, lnb, ca, rw, wbs, 16);
        hipLaunchKernelGGL(k_u2,     dim3(4096),   dim3(64),   0, stream, sa, ca, c1b, u);
        hipLaunchKernelGGL(k_a,      dim3(32),     dim3(256),  0, stream, u, sw1, sw2, aw);
        hipLaunchKernelGGL(k_stats4, dim3(4096),   dim3(256),  0, stream, xbf, sa, c1b, ca, aw, rb, st4);
        hipLaunchKernelGGL(k_out3,   dim3(32, 64), dim3(256),  0, stream, xbf, wbs, sa, c1b, st4, out);
    } else {
        float* sa      = ws;                       // 131072
        float* xs_part = ws + 131072;              // 32768
        float* ca      = ws + 163840;              // 8192
        float* u       = ws + 172032;              // 8192
        float* aw      = ws + 180224;              // 8192
        f32x4* st4     = (f32x4*)(ws + 188416);    // 32768 floats
        unsigned short* wbs = (unsigned short*)(ws + 221184);  // 65536 bf16

        hipMemsetAsync(sa, 0, (size_t)B_ * HW_ * sizeof(float), stream);
        hipLaunchKernelGGL(k_pass1, dim3(4, 32, 8), dim3(256), 0, stream, x, c1w, sa, xs_part);
        hipLaunchKernelGGL(k_ca,    dim3(32),       dim3(256), 0, stream, xs_part, c0w, c0b, b1w, b1b, lng, lnb, ca, rw, wbs, 4);
        hipLaunchKernelGGL(k_u,     dim3(8192),     dim3(64),  0, stream, sa, ca, c1b, u);
        hipLaunchKernelGGL(k_a,     dim3(32),       dim3(256), 0, stream, u, sw1, sw2, aw);
        hipLaunchKernelGGL(k_stats, dim3(8192),     dim3(256), 0, stream, x, sa, c1b, ca, aw, rb, st4);
        hipLaunchKernelGGL(k_out,   dim3(32, 64),   dim3(256), 0, stream, x, wbs, sa, c1b, st4, out);
    }
}

// Round 10
// 144.868 us; speedup vs baseline: 1.0428x; 1.0428x over previous
//
#include <hip/hip_runtime.h>
#include <math.h>

#define B_  32
#define C_  256
#define HW_ 4096
#define LN_EPS 1e-5f

typedef __attribute__((ext_vector_type(4))) float f32x4;
typedef __attribute__((ext_vector_type(8))) short bf16x8;
typedef __attribute__((ext_vector_type(4))) unsigned u32x4;
typedef __attribute__((ext_vector_type(2))) unsigned u32x2;

__device__ __forceinline__ float hsig(float v) {
    return fminf(fmaxf((v + 3.0f) * (1.0f / 6.0f), 0.0f), 1.0f);
}
// softmax logit: a*hsig(ca*sa) + (1-a)*hsig(ca+sa); always in [0,1]
__device__ __forceinline__ float tval(float ca, float a, float sav) {
    return a * hsig(ca * sav) + (1.0f - a) * hsig(ca + sav);
}
__device__ __forceinline__ unsigned short f2bf(float f) {
    unsigned u = __float_as_uint(f);
    unsigned r = (u + 0x7fffu + ((u >> 16) & 1u)) >> 16;   // RNE
    return (unsigned short)r;
}
__device__ __forceinline__ float bf2f(unsigned short h) {
    return __uint_as_float(((unsigned)h) << 16);
}
// Bs swizzle: conflict-free for b64 staging writes, b128 B-frag reads, 8B epilogue reads
__device__ __forceinline__ int bswz(int n) {
    return ((n & 7) ^ ((n >> 3) & 7)) << 4;
}

// =====================================================================
// NEW PATH: xbf in natural [b][c][hw] bf16 layout.
// =====================================================================

// ---- K1 (round-8 proven form): one x pass -> sa + xs partials + xbf ----
// Block (hwq 16, b 32) x 1024 thr (16 waves): 2 blocks/CU -> 32 waves/CU (8/SIMD).
// Wave w handles c = i*16 + w; lanes cover 256 hw via f32x4 (4 hw/lane).
// NOTE (round 9 lesson): NO nontemporal loads on x — ~half of x is L3-resident
// across bench iterations (round-2 FETCH evidence); nt-loads broke that (-5us).
// NO launch_bounds reg pin + unroll stays 4 (spill risk, round-7 lesson).
__global__ __launch_bounds__(1024) void k_pass1c(
    const float* __restrict__ x, const float* __restrict__ w1,
    float* __restrict__ sa, float* __restrict__ xs_part,
    unsigned short* __restrict__ xbf)
{
    __shared__ float sw1[C_];
    __shared__ float sred[16][256];
    __shared__ float xsl[C_];
    int hwq = blockIdx.x, b = blockIdx.y;
    int tid = threadIdx.x, w = tid >> 6, l = tid & 63;
    int hw0 = hwq * 256;
    if (tid < 256) sw1[tid] = w1[tid];
    __syncthreads();
    const float* xb = x + (size_t)b * (C_ * HW_) + hw0 + l * 4;
    unsigned short* xo = xbf + (size_t)b * (C_ * HW_) + hw0 + l * 4;
    f32x4 sacc = {0.f, 0.f, 0.f, 0.f};
    #pragma unroll 4
    for (int i = 0; i < 16; ++i) {
        int c = i * 16 + w;
        f32x4 v = *(const f32x4*)(xb + (size_t)c * HW_);
        sacc += sw1[c] * v;
        ushort4 o = { f2bf(v.x), f2bf(v.y), f2bf(v.z), f2bf(v.w) };
        *(ushort4*)(xo + (size_t)c * HW_) = o;
        float h = (v.x + v.y) + (v.z + v.w);
        h += __shfl_xor(h, 32); h += __shfl_xor(h, 16); h += __shfl_xor(h, 8);
        h += __shfl_xor(h, 4);  h += __shfl_xor(h, 2);  h += __shfl_xor(h, 1);
        if (l == 0) xsl[c] = h;
    }
    *(f32x4*)&sred[w][l * 4] = sacc;
    __syncthreads();
    if (tid < 256) {
        float s = 0.f;
        #pragma unroll
        for (int g = 0; g < 16; ++g) s += sred[g][tid];
        sa[(size_t)b * HW_ + hw0 + tid] = s;
        xs_part[((size_t)hwq * B_ + b) * C_ + tid] = xsl[tid];
    }
}

// ---- K2: ca = LN(hsig(bn1(conv0(mean))))  [+ fused res_w->bf16 cvt] (both paths)
__global__ void k_ca(const float* __restrict__ xs_part, const float* __restrict__ w0,
                     const float* __restrict__ b0, const float* __restrict__ w1,
                     const float* __restrict__ b1, const float* __restrict__ g,
                     const float* __restrict__ be, float* __restrict__ ca,
                     const float* __restrict__ rw, unsigned short* __restrict__ wbs,
                     int nparts) {
    int b = blockIdx.x, tid = threadIdx.x;  // 256
    __shared__ float xm[C_], t0[128], red[4];
    float xs = 0.f;
    for (int i = 0; i < nparts; ++i)
        xs += xs_part[((size_t)i * B_ + b) * C_ + tid];
    xm[tid] = xs * (1.0f / HW_);
    __syncthreads();
    if (tid < 128) {
        float s = b0[tid];
        const float* wr = w0 + tid * C_;
        for (int c = 0; c < C_; ++c) s += wr[c] * xm[c];
        t0[tid] = s;
    }
    __syncthreads();
    float s = b1[tid];
    const float* wr = w1 + tid * 128;
    for (int o = 0; o < 128; ++o) s += wr[o] * t0[o];
    float v = hsig(s);
    float sum = v;
    #pragma unroll
    for (int o = 32; o; o >>= 1) sum += __shfl_xor(sum, o);
    if ((tid & 63) == 0) red[tid >> 6] = sum;
    __syncthreads();
    float mu = (red[0] + red[1] + red[2] + red[3]) * (1.0f / C_);
    __syncthreads();
    float d = v - mu;
    float sq = d * d;
    #pragma unroll
    for (int o = 32; o; o >>= 1) sq += __shfl_xor(sq, o);
    if ((tid & 63) == 0) red[tid >> 6] = sq;
    __syncthreads();
    float var = (red[0] + red[1] + red[2] + red[3]) * (1.0f / C_);
    ca[b * C_ + tid] = d * (1.0f / sqrtf(var + LN_EPS)) * g[tid] + be[tid];

    // ---- fused: res_w fp32 -> bf16 in MFMA A-fragment order ----
    int gid = b * 256 + tid;
    int lane = gid & 63;
    int mi = (gid >> 6) & 3;
    int ks = (gid >> 8) & 7;
    int wv2 = gid >> 11;
    int m = wv2 * 64 + mi * 16 + (lane & 15);
    int kb = ks * 32 + (lane >> 4) * 8;
    const float* src = rw + m * C_ + kb;
    f32x4 a4 = *(const f32x4*)src;
    f32x4 b4 = *(const f32x4*)(src + 4);
    ushort4 o0 = { f2bf(a4.x), f2bf(a4.y), f2bf(a4.z), f2bf(a4.w) };
    ushort4 o1 = { f2bf(b4.x), f2bf(b4.y), f2bf(b4.z), f2bf(b4.w) };
    unsigned short* dst = wbs + (size_t)gid * 8;
    *(ushort4*)dst = o0;
    *(ushort4*)(dst + 4) = o1;
}

// ---- K3n: u for 2 channels per block (sa loads shared) ----
__global__ void k_u2(const float* __restrict__ sa, const float* __restrict__ ca,
                     const float* __restrict__ b1, float* __restrict__ u) {
    int bc = blockIdx.x;              // 4096
    int b = bc >> 7, c0 = (bc & 127) * 2;
    int tid = threadIdx.x;            // 64
    float ca0 = ca[b * C_ + c0], ca1 = ca[b * C_ + c0 + 1];
    float bias = b1[0];
    const float* sp = sa + (size_t)b * HW_;
    float s0 = 0.f, s1 = 0.f;
    for (int i = 0; i < 16; ++i) {
        f32x4 v = *(const f32x4*)(sp + i * 256 + tid * 4);
        #pragma unroll
        for (int j = 0; j < 4; ++j) {
            float sv = v[j] + bias;
            s0 += hsig(ca0 * sv) + hsig(ca0 + sv);
            s1 += hsig(ca1 * sv) + hsig(ca1 + sv);
        }
    }
    #pragma unroll
    for (int o = 32; o; o >>= 1) { s0 += __shfl_xor(s0, o); s1 += __shfl_xor(s1, o); }
    if (tid == 0) {
        u[b * C_ + c0]     = s0 * (1.0f / HW_);
        u[b * C_ + c0 + 1] = s1 * (1.0f / HW_);
    }
}

// ---- K4: a[b,c] = softmax_c(sk_w2 @ (sk_w1 @ u)) (both paths) ----
__global__ void k_a(const float* __restrict__ u, const float* __restrict__ w1,
                    const float* __restrict__ w2, float* __restrict__ aout) {
    int b = blockIdx.x, tid = threadIdx.x;  // 256
    __shared__ float uu[C_], v0[128], red[4];
    uu[tid] = u[b * C_ + tid];
    __syncthreads();
    if (tid < 128) {
        float s = 0.f;
        const float* wr = w1 + tid * C_;
        for (int c = 0; c < C_; ++c) s += wr[c] * uu[c];
        v0[tid] = s;
    }
    __syncthreads();
    float s = 0.f;
    const float* wr = w2 + tid * 128;
    for (int o = 0; o < 128; ++o) s += wr[o] * v0[o];
    float m = s;
    #pragma unroll
    for (int o = 32; o; o >>= 1) m = fmaxf(m, __shfl_xor(m, o));
    if ((tid & 63) == 0) red[tid >> 6] = m;
    __syncthreads();
    m = fmaxf(fmaxf(red[0], red[1]), fmaxf(red[2], red[3]));
    __syncthreads();
    float e = __expf(s - m);
    float se = e;
    #pragma unroll
    for (int o = 32; o; o >>= 1) se += __shfl_xor(se, o);
    if ((tid & 63) == 0) red[tid >> 6] = se;
    __syncthreads();
    float tot = red[0] + red[1] + red[2] + red[3];
    aout[b * C_ + tid] = e / tot;
}

// ---- K5n: row stats for 2 channels per block (sa loads shared, xbf bf16) ----
__global__ void k_stats4(const unsigned short* __restrict__ xbf, const float* __restrict__ sa,
                         const float* __restrict__ b1,
                         const float* __restrict__ ca, const float* __restrict__ aw,
                         const float* __restrict__ res_b, f32x4* __restrict__ st4) {
    int blk = blockIdx.x;             // 4096
    int b = blk >> 7, c0 = (blk & 127) * 2;
    int bc0 = b * C_ + c0;
    int tid = threadIdx.x;            // 256
    float ca0 = ca[bc0],     a0 = aw[bc0];
    float ca1 = ca[bc0 + 1], a1 = aw[bc0 + 1];
    float bias = b1[0];
    const float* sp = sa + (size_t)b * HW_;
    const unsigned* xp0 = (const unsigned*)(xbf + (size_t)bc0 * HW_);
    const unsigned* xp1 = (const unsigned*)(xbf + (size_t)(bc0 + 1) * HW_);
    float se0 = 0.f, xe0 = 0.f, se1 = 0.f, xe1 = 0.f;
    #pragma unroll
    for (int i = 0; i < 4; ++i) {
        f32x4 s4 = *(const f32x4*)(sp + i * 1024 + tid * 4);
        u32x2 xa = *(const u32x2*)(xp0 + i * 512 + tid * 2);
        u32x2 xc = *(const u32x2*)(xp1 + i * 512 + tid * 2);
        float va[4], vc[4];
        va[0] = bf2f((unsigned short)(xa[0] & 0xffffu));
        va[1] = bf2f((unsigned short)(xa[0] >> 16));
        va[2] = bf2f((unsigned short)(xa[1] & 0xffffu));
        va[3] = bf2f((unsigned short)(xa[1] >> 16));
        vc[0] = bf2f((unsigned short)(xc[0] & 0xffffu));
        vc[1] = bf2f((unsigned short)(xc[0] >> 16));
        vc[2] = bf2f((unsigned short)(xc[1] & 0xffffu));
        vc[3] = bf2f((unsigned short)(xc[1] >> 16));
        #pragma unroll
        for (int j = 0; j < 4; ++j) {
            float sv = s4[j] + bias;
            float e0 = __expf(tval(ca0, a0, sv));
            float e1 = __expf(tval(ca1, a1, sv));
            se0 += e0; xe0 += va[j] * e0;
            se1 += e1; xe1 += vc[j] * e1;
        }
    }
    __shared__ float red[4][4];
    #pragma unroll
    for (int o = 32; o; o >>= 1) {
        se0 += __shfl_xor(se0, o); xe0 += __shfl_xor(xe0, o);
        se1 += __shfl_xor(se1, o); xe1 += __shfl_xor(xe1, o);
    }
    if ((tid & 63) == 0) {
        int w = tid >> 6;
        red[0][w] = se0; red[1][w] = xe0; red[2][w] = se1; red[3][w] = xe1;
    }
    __syncthreads();
    if (tid == 0) {
        float S0 = red[0][0] + red[0][1] + red[0][2] + red[0][3];
        float X0 = red[1][0] + red[1][1] + red[1][2] + red[1][3];
        float S1 = red[2][0] + red[2][1] + red[2][2] + red[2][3];
        float X1 = red[3][0] + red[3][1] + red[3][2] + red[3][3];
        float r0 = 1.0f / S0, r1 = 1.0f / S1;
        f32x4 st0 = { ca0, a0, r0, X0 * r0 + res_b[c0] };
        f32x4 st1 = { ca1, a1, r1, X1 * r1 + res_b[c0 + 1] };
        st4[bc0] = st0;
        st4[bc0 + 1] = st1;
    }
}

// ---- K6b: out = res_w@x (bf16 MFMA) + x*p + addv.
// launch_bounds (256,3): VGPR 104, no spills (round-7 lesson: (256,4) pinned
// VGPR to 64 and spilled, +60MB scratch). nontemporal out stores keep the
// 134MB write stream out of L2/L3 (FETCH 68->44MB measured in round 7).
__global__ __launch_bounds__(256, 3) void k_out3(
    const unsigned short* __restrict__ xbf, const unsigned short* __restrict__ wbs,
    const float* __restrict__ sa, const float* __restrict__ b1,
    const f32x4* __restrict__ st4, float* __restrict__ out)
{
    __shared__ __align__(16) unsigned short Bs[64 * 256];  // [n][k-pair] bf16, swizzled, 32 KB
    __shared__ f32x4 sst[C_];
    __shared__ float ssa[64];

    int b = blockIdx.x, tile = blockIdx.y;
    int n0 = tile * 64;
    int tid = threadIdx.x;       // 256
    int w = tid >> 6, lane = tid & 63;
    int hwc = tid & 7;           // 8-hw chunk within the 64-wide tile
    int cq  = tid >> 3;          // 0..31 -> 4 consecutive c rows per iteration

    // ---- issue staging loads first (overlap with af/sst/ssa loads) ----
    const unsigned short* xb = xbf + (size_t)b * (C_ * HW_) + n0 + hwc * 8;
    u32x4 ld[2][4];
    #pragma unroll
    for (int it = 0; it < 2; ++it) {
        int c0 = it * 128 + cq * 4;
        #pragma unroll
        for (int r = 0; r < 4; ++r)
            ld[it][r] = *(const u32x4*)(xb + (size_t)(c0 + r) * HW_);
    }

    bf16x8 af[2][4];
    const bf16x8* wp = (const bf16x8*)wbs;
    #pragma unroll
    for (int ks2 = 0; ks2 < 2; ++ks2)
        #pragma unroll
        for (int mi = 0; mi < 4; ++mi)
            af[ks2][mi] = wp[(size_t)(((w * 8 + ks2) * 4 + mi) * 64 + lane)];

    sst[tid] = st4[b * C_ + tid];
    if (tid < 64) ssa[tid] = sa[(size_t)b * HW_ + n0 + tid] + b1[0];

    // ---- interleave c-pairs + swizzled ds_write_b64 ----
    #pragma unroll
    for (int it = 0; it < 2; ++it) {
        int kp0 = it * 64 + cq * 2;
        #pragma unroll
        for (int e = 0; e < 8; ++e) {
            int n = hwc * 8 + e;
            unsigned a0 = ld[it][0][e >> 1], b0v = ld[it][1][e >> 1];
            unsigned a1 = ld[it][2][e >> 1], b1v = ld[it][3][e >> 1];
            unsigned d0, d1;
            if (e & 1) {
                d0 = (a0 >> 16) | (b0v & 0xffff0000u);
                d1 = (a1 >> 16) | (b1v & 0xffff0000u);
            } else {
                d0 = (a0 & 0xffffu) | (b0v << 16);
                d1 = (a1 & 0xffffu) | (b1v << 16);
            }
            int bo = (n * 512 + kp0 * 4) ^ bswz(n);
            u32x2 dd = { d0, d1 };
            *(u32x2*)((char*)Bs + bo) = dd;
        }
    }
    __syncthreads();

    f32x4 acc[4][4];
    #pragma unroll
    for (int i = 0; i < 4; ++i)
        #pragma unroll
        for (int j = 0; j < 4; ++j) acc[i][j] = (f32x4){0.f, 0.f, 0.f, 0.f};

    #pragma unroll
    for (int ksg = 0; ksg < 4; ++ksg) {
        #pragma unroll
        for (int ks2 = 0; ks2 < 2; ++ks2) {
            int ks = ksg * 2 + ks2;
            bf16x8 bfr[4];
            #pragma unroll
            for (int ni = 0; ni < 4; ++ni) {
                int n = ni * 16 + (lane & 15);
                int bo = (n * 512 + ks * 64 + (lane >> 4) * 16) ^ bswz(n);
                bfr[ni] = *(const bf16x8*)((const char*)Bs + bo);
            }
            #pragma unroll
            for (int mi = 0; mi < 4; ++mi)
                #pragma unroll
                for (int ni = 0; ni < 4; ++ni)
                    acc[mi][ni] = __builtin_amdgcn_mfma_f32_16x16x32_bf16(
                        af[ks2][mi], bfr[ni], acc[mi][ni], 0, 0, 0);
            if (ksg < 3) {   // reload this half for the next K-group (overlaps MFMAs)
                #pragma unroll
                for (int mi = 0; mi < 4; ++mi)
                    af[ks2][mi] = wp[(size_t)(((w * 8 + (ksg + 1) * 2 + ks2) * 4 + mi) * 64 + lane)];
            }
        }
    }

    // epilogue: out = acc + x*p + addv   (x re-read as bf16 from Bs; p = exp(t)/S)
    float* ob = out + (size_t)b * (C_ * HW_) + n0;
    #pragma unroll
    for (int mi = 0; mi < 4; ++mi) {
        int m0 = w * 64 + mi * 16 + (lane >> 4) * 4;
        f32x4 s0 = sst[m0 + 0];
        f32x4 s1 = sst[m0 + 1];
        f32x4 s2 = sst[m0 + 2];
        f32x4 s3 = sst[m0 + 3];
        #pragma unroll
        for (int ni = 0; ni < 4; ++ni) {
            int n = ni * 16 + (lane & 15);
            float sav = ssa[n];
            int bo = (n * 512 + m0 * 2) ^ bswz(n);
            ushort4 xv = *(const ushort4*)((const char*)Bs + bo);
            float o0 = acc[mi][ni][0] + bf2f(xv.x) * (__expf(tval(s0.x, s0.y, sav)) * s0.z) + s0.w;
            float o1 = acc[mi][ni][1] + bf2f(xv.y) * (__expf(tval(s1.x, s1.y, sav)) * s1.z) + s1.w;
            float o2 = acc[mi][ni][2] + bf2f(xv.z) * (__expf(tval(s2.x, s2.y, sav)) * s2.z) + s2.w;
            float o3 = acc[mi][ni][3] + bf2f(xv.w) * (__expf(tval(s3.x, s3.y, sav)) * s3.z) + s3.w;
            __builtin_nontemporal_store(o0, &ob[(size_t)(m0 + 0) * HW_ + n]);
            __builtin_nontemporal_store(o1, &ob[(size_t)(m0 + 1) * HW_ + n]);
            __builtin_nontemporal_store(o2, &ob[(size_t)(m0 + 2) * HW_ + n]);
            __builtin_nontemporal_store(o3, &ob[(size_t)(m0 + 3) * HW_ + n]);
        }
    }
}

// =====================================================================
// OLD PATH (fallback when workspace too small) — unchanged kernels
// =====================================================================

__global__ void k_pass1(const float* __restrict__ x, const float* __restrict__ w1,
                        float* __restrict__ sa, float* __restrict__ xs_part)
{
    int tid = threadIdx.x, wave = tid >> 6, lane = tid & 63;
    int hwq = blockIdx.x, b = blockIdx.y, ct = blockIdx.z;
    int c0 = ct * 32;
    int hw0 = hwq * 1024;
    const float* xb = x + (size_t)b * (C_ * HW_) + hw0 + tid * 4;
    __shared__ float part[32 * 4];
    f32x4 sacc = {0.f, 0.f, 0.f, 0.f};
    #pragma unroll 4
    for (int cc = 0; cc < 32; ++cc) {
        int c = c0 + cc;
        f32x4 v = *(const f32x4*)(xb + (size_t)c * HW_);
        float wv = w1[c];
        sacc += wv * v;
        float h = (v.x + v.y) + (v.z + v.w);
        h += __shfl_xor(h, 32); h += __shfl_xor(h, 16); h += __shfl_xor(h, 8);
        h += __shfl_xor(h, 4);  h += __shfl_xor(h, 2);  h += __shfl_xor(h, 1);
        if (lane == 0) part[cc * 4 + wave] = h;
    }
    float* sp = sa + (size_t)b * HW_ + hw0 + tid * 4;
    atomicAdd(sp + 0, sacc.x);
    atomicAdd(sp + 1, sacc.y);
    atomicAdd(sp + 2, sacc.z);
    atomicAdd(sp + 3, sacc.w);
    __syncthreads();
    if (tid < 32)
        xs_part[((size_t)hwq * B_ + b) * C_ + c0 + tid] =
            part[tid * 4 + 0] + part[tid * 4 + 1] + part[tid * 4 + 2] + part[tid * 4 + 3];
}

__global__ void k_u(const float* __restrict__ sa, const float* __restrict__ ca,
                    const float* __restrict__ b1, float* __restrict__ u) {
    int bc = blockIdx.x;
    int b = bc >> 8;
    int tid = threadIdx.x;  // 64
    float cav = ca[bc];
    float bias = b1[0];
    const float* sp = sa + (size_t)b * HW_;
    float s = 0.f;
    for (int i = 0; i < 16; ++i) {
        f32x4 v = *(const f32x4*)(sp + i * 256 + tid * 4);
        #pragma unroll
        for (int j = 0; j < 4; ++j) {
            float sv = v[j] + bias;
            s += hsig(cav * sv) + hsig(cav + sv);
        }
    }
    #pragma unroll
    for (int o = 32; o; o >>= 1) s += __shfl_xor(s, o);
    if (tid == 0) u[bc] = s * (1.0f / HW_);
}

__global__ void k_stats(const float* __restrict__ x, const float* __restrict__ sa,
                        const float* __restrict__ b1,
                        const float* __restrict__ ca, const float* __restrict__ aw,
                        const float* __restrict__ res_b, f32x4* __restrict__ st4) {
    int bc = blockIdx.x;
    int b = bc >> 8, c = bc & 255;
    int tid = threadIdx.x;  // 256
    float cav = ca[bc], av = aw[bc];
    float bias = b1[0];
    const float* sp = sa + (size_t)b * HW_;
    const float* xp = x + (size_t)bc * HW_;
    float se = 0.f, xe = 0.f;
    #pragma unroll
    for (int i = 0; i < 4; ++i) {
        f32x4 s4 = *(const f32x4*)(sp + i * 1024 + tid * 4);
        f32x4 x4 = *(const f32x4*)(xp + i * 1024 + tid * 4);
        #pragma unroll
        for (int j = 0; j < 4; ++j) {
            float e = __expf(tval(cav, av, s4[j] + bias));
            se += e;
            xe += x4[j] * e;
        }
    }
    __shared__ float red[4], red2[4];
    #pragma unroll
    for (int o = 32; o; o >>= 1) { se += __shfl_xor(se, o); xe += __shfl_xor(xe, o); }
    if ((tid & 63) == 0) { red[tid >> 6] = se; red2[tid >> 6] = xe; }
    __syncthreads();
    if (tid == 0) {
        float S = red[0] + red[1] + red[2] + red[3];
        float X = red2[0] + red2[1] + red2[2] + red2[3];
        float rcp = 1.0f / S;
        f32x4 st = { cav, av, rcp, X * rcp + res_b[c] };
        st4[bc] = st;
    }
}

__global__ __launch_bounds__(256, 2) void k_out(
    const float* __restrict__ x, const unsigned short* __restrict__ wbs,
    const float* __restrict__ sa, const float* __restrict__ b1,
    const f32x4* __restrict__ st4, float* __restrict__ out)
{
    __shared__ __align__(16) unsigned short Bs[64 * 256];
    __shared__ f32x4 sst[C_];
    __shared__ float ssa[64];

    int b = blockIdx.x, tile = blockIdx.y;
    int n0 = tile * 64;
    int tid = threadIdx.x;
    int w = tid >> 6, lane = tid & 63;

    const float* xb = x + (size_t)b * (C_ * HW_);

    bf16x8 af[8][4];
    #pragma unroll
    for (int ks = 0; ks < 8; ++ks)
        #pragma unroll
        for (int mi = 0; mi < 4; ++mi)
            af[ks][mi] = *(const bf16x8*)(wbs + (size_t)(((w * 8 + ks) * 4 + mi) * 64 + lane) * 8);

    sst[tid] = st4[b * C_ + tid];
    if (tid < 64) ssa[tid] = sa[(size_t)b * HW_ + n0 + tid] + b1[0];

    #pragma unroll
    for (int p2 = 0; p2 < 8; ++p2) {
        int id = p2 * 256 + tid;
        int kp = id >> 4;
        int tcn = id & 15;
        const float* g0 = xb + (size_t)(2 * kp) * HW_ + n0 + 4 * tcn;
        f32x4 v0 = *(const f32x4*)g0;
        f32x4 v1 = *(const f32x4*)(g0 + HW_);
        #pragma unroll
        for (int i = 0; i < 4; ++i) {
            int n = 4 * tcn + i;
            unsigned val = (unsigned)f2bf(v0[i]) | ((unsigned)f2bf(v1[i]) << 16);
            int bo = (n * 512 + kp * 4) ^ ((n & 7) << 4);
            *(unsigned*)((char*)Bs + bo) = val;
        }
    }
    __syncthreads();

    f32x4 acc[4][4];
    #pragma unroll
    for (int i = 0; i < 4; ++i)
        #pragma unroll
        for (int j = 0; j < 4; ++j) acc[i][j] = (f32x4){0.f, 0.f, 0.f, 0.f};

    #pragma unroll
    for (int ks = 0; ks < 8; ++ks) {
        bf16x8 bfr[4];
        #pragma unroll
        for (int ni = 0; ni < 4; ++ni) {
            int n = ni * 16 + (lane & 15);
            int bo = (n * 512 + ks * 64 + (lane >> 4) * 16) ^ ((n & 7) << 4);
            bfr[ni] = *(const bf16x8*)((const char*)Bs + bo);
        }
        #pragma unroll
        for (int mi = 0; mi < 4; ++mi)
            #pragma unroll
            for (int ni = 0; ni < 4; ++ni)
                acc[mi][ni] = __builtin_amdgcn_mfma_f32_16x16x32_bf16(
                    af[ks][mi], bfr[ni], acc[mi][ni], 0, 0, 0);
    }

    float* ob = out + (size_t)b * (C_ * HW_) + n0;
    #pragma unroll
    for (int mi = 0; mi < 4; ++mi) {
        int m0 = w * 64 + mi * 16 + (lane >> 4) * 4;
        f32x4 s0 = sst[m0 + 0];
        f32x4 s1 = sst[m0 + 1];
        f32x4 s2 = sst[m0 + 2];
        f32x4 s3 = sst[m0 + 3];
        #pragma unroll
        for (int ni = 0; ni < 4; ++ni) {
            int n = ni * 16 + (lane & 15);
            float sav = ssa[n];
            int bo = (n * 512 + m0 * 2) ^ ((n & 7) << 4);
            ushort4 xv = *(const ushort4*)((const char*)Bs + bo);
            float o0 = acc[mi][ni][0] + bf2f(xv.x) * (__expf(tval(s0.x, s0.y, sav)) * s0.z) + s0.w;
            float o1 = acc[mi][ni][1] + bf2f(xv.y) * (__expf(tval(s1.x, s1.y, sav)) * s1.z) + s1.w;
            float o2 = acc[mi][ni][2] + bf2f(xv.z) * (__expf(tval(s2.x, s2.y, sav)) * s2.z) + s2.w;
            float o3 = acc[mi][ni][3] + bf2f(xv.w) * (__expf(tval(s3.x, s3.y, sav)) * s3.z) + s3.w;
            ob[(size_t)(m0 + 0) * HW_ + n] = o0;
            ob[(size_t)(m0 + 1) * HW_ + n] = o1;
            ob[(size_t)(m0 + 2) * HW_ + n] = o2;
            ob[(size_t)(m0 + 3) * HW_ + n] = o3;
        }
    }
}

extern "C" void kernel_launch(void* const* d_in, const int* in_sizes, int n_in,
                              void* d_out, int out_size, void* d_ws, size_t ws_size,
                              hipStream_t stream) {
    (void)in_sizes; (void)n_in; (void)out_size;
    const float* x   = (const float*)d_in[0];
    const float* c0w = (const float*)d_in[1];
    const float* c0b = (const float*)d_in[2];
    const float* b1w = (const float*)d_in[3];
    const float* b1b = (const float*)d_in[4];
    const float* c1w = (const float*)d_in[5];
    const float* c1b = (const float*)d_in[6];
    const float* lng = (const float*)d_in[7];
    const float* lnb = (const float*)d_in[8];
    const float* sw1 = (const float*)d_in[9];
    const float* sw2 = (const float*)d_in[10];
    const float* rw  = (const float*)d_in[11];
    const float* rb  = (const float*)d_in[12];
    float* out = (float*)d_out;
    float* ws = (float*)d_ws;

    const size_t NEW_WS_FLOATS = (size_t)352256 + 16777216;   // ~68.5 MB
    if (ws_size >= NEW_WS_FLOATS * sizeof(float)) {
        float* sa      = ws;                         // 131072
        float* xs_part = ws + 131072;                // 16*32*256 = 131072
        float* ca      = ws + 262144;                // 8192
        float* u       = ws + 270336;                // 8192
        float* aw      = ws + 278528;                // 8192
        f32x4* st4     = (f32x4*)(ws + 286720);      // 32768 floats
        unsigned short* wbs = (unsigned short*)(ws + 319488);   // 65536 bf16
        unsigned short* xbf = (unsigned short*)(ws + 352256);   // 67.1 MB bf16 [b][c][hw]

        hipLaunchKernelGGL(k_pass1c, dim3(16, 32), dim3(1024), 0, stream, x, c1w, sa, xs_part, xbf);
        hipLaunchKernelGGL(k_ca,     dim3(32),     dim3(256),  0, stream, xs_part, c0w, c0b, b1w, b1b, lng, lnb, ca, rw, wbs, 16);
        hipLaunchKernelGGL(k_u2,     dim3(4096),   dim3(64),   0, stream, sa, ca, c1b, u);
        hipLaunchKernelGGL(k_a,      dim3(32),     dim3(256),  0, stream, u, sw1, sw2, aw);
        hipLaunchKernelGGL(k_stats4, dim3(4096),   dim3(256),  0, stream, xbf, sa, c1b, ca, aw, rb, st4);
        hipLaunchKernelGGL(k_out3,   dim3(32, 64), dim3(256),  0, stream, xbf, wbs, sa, c1b, st4, out);
    } else {
        float* sa      = ws;                       // 131072
        float* xs_part = ws + 131072;              // 32768
        float* ca      = ws + 163840;              // 8192
        float* u       = ws + 172032;              // 8192
        float* aw      = ws + 180224;              // 8192
        f32x4* st4     = (f32x4*)(ws + 188416);    // 32768 floats
        unsigned short* wbs = (unsigned short*)(ws + 221184);  // 65536 bf16

        hipMemsetAsync(sa, 0, (size_t)B_ * HW_ * sizeof(float), stream);
        hipLaunchKernelGGL(k_pass1, dim3(4, 32, 8), dim3(256), 0, stream, x, c1w, sa, xs_part);
        hipLaunchKernelGGL(k_ca,    dim3(32),       dim3(256), 0, stream, xs_part, c0w, c0b, b1w, b1b, lng, lnb, ca, rw, wbs, 4);
        hipLaunchKernelGGL(k_u,     dim3(8192),     dim3(64),  0, stream, sa, ca, c1b, u);
        hipLaunchKernelGGL(k_a,     dim3(32),       dim3(256), 0, stream, u, sw1, sw2, aw);
        hipLaunchKernelGGL(k_stats, dim3(8192),     dim3(256), 0, stream, x, sa, c1b, ca, aw, rb, st4);
        hipLaunchKernelGGL(k_out,   dim3(32, 64),   dim3(256), 0, stream, x, wbs, sa, c1b, st4, out);
    }
}